// Round 1
// baseline (467.444 us; speedup 1.0000x reference)
//
#include <hip/hip_runtime.h>
#include <cmath>

#define N_NODES 50000
#define N_EDGES 800000
#define D 64
#define N_REL 8

// ---------------------------------------------------------------------------
// Kernel 1: w[r*128 + j] = sum_k W_r[r][j][k]   (8 x 128 rows, 64-elem sums)
// ---------------------------------------------------------------------------
__global__ void wprep_kernel(const float* __restrict__ W_r, float* __restrict__ w) {
    int t = blockIdx.x * blockDim.x + threadIdx.x;   // 0 .. 1023
    if (t >= N_REL * 2 * D) return;
    const float* p = W_r + (size_t)t * D;
    float s = 0.0f;
#pragma unroll
    for (int k = 0; k < D; ++k) s += p[k];
    w[t] = s;
}

// ---------------------------------------------------------------------------
// Kernel 2: per-edge gate + atomic scatter into agg_sum / cnt.
// One wave (64 lanes) per edge; lane i handles feature dim i.
// ---------------------------------------------------------------------------
__global__ __launch_bounds__(256) void edge_kernel(
    const float* __restrict__ x,
    const int*   __restrict__ src,
    const int*   __restrict__ dst,
    const int*   __restrict__ rel,
    const float* __restrict__ w,      // (N_REL, 128): [r*128+j] j<64 = w_dst, j>=64 = w_src
    float* __restrict__ agg_sum,      // (N_NODES, 64)
    float* __restrict__ cnt)          // (N_NODES)
{
    int wave = (blockIdx.x * blockDim.x + threadIdx.x) >> 6;
    int lane = threadIdx.x & 63;
    if (wave >= N_EDGES) return;

    int s = src[wave];
    int d = dst[wave];
    int r = rel[wave];

    float xs = x[(size_t)s * D + lane];
    float xd = x[(size_t)d * D + lane];
    float wd = w[r * 128 + lane];
    float wsr = w[r * 128 + 64 + lane];

    float p = xd * wd + xs * wsr;
    // butterfly reduce across 64 lanes -> every lane holds the logit
#pragma unroll
    for (int off = 32; off >= 1; off >>= 1)
        p += __shfl_xor(p, off, 64);

    float gate = 1.0f / (1.0f + __expf(-p));

    atomicAdd(&agg_sum[(size_t)d * D + lane], xs * gate);
    if (lane == 0) atomicAdd(&cnt[d], 1.0f);
}

// ---------------------------------------------------------------------------
// Kernel 3: per-node  out = leaky_relu(W_lin @ [x[n], agg[n]] + b)
// One wave per node; lane j computes output feature j.
// combined[128] staged in LDS (same-address broadcast reads, conflict-free).
// ---------------------------------------------------------------------------
__global__ __launch_bounds__(256) void node_kernel(
    const float* __restrict__ x,
    const float* __restrict__ agg_sum,
    const float* __restrict__ cnt,
    const float* __restrict__ W_lin,   // (64, 128) row-major
    const float* __restrict__ b_lin,   // (64)
    float* __restrict__ out)           // (N_NODES, 64)
{
    __shared__ float c[4][128];
    int wid  = threadIdx.x >> 6;
    int lane = threadIdx.x & 63;
    int node = blockIdx.x * 4 + wid;
    bool valid = (node < N_NODES);

    if (valid) {
        float cn  = cnt[node];
        float inv = 1.0f / fmaxf(cn, 1.0f);
        c[wid][lane]      = x[(size_t)node * D + lane];
        c[wid][64 + lane] = agg_sum[(size_t)node * D + lane] * inv;
    }
    __syncthreads();

    if (valid) {
        const float* wrow = W_lin + lane * 128;
        float acc = b_lin[lane];
#pragma unroll
        for (int k = 0; k < 128; k += 4) {
            float4 w4 = *(const float4*)(wrow + k);
            float4 c4 = *(const float4*)(&c[wid][k]);
            acc += w4.x * c4.x + w4.y * c4.y + w4.z * c4.z + w4.w * c4.w;
        }
        out[(size_t)node * D + lane] = (acc > 0.0f) ? acc : 0.01f * acc;
    }
}

// ---------------------------------------------------------------------------
extern "C" void kernel_launch(void* const* d_in, const int* in_sizes, int n_in,
                              void* d_out, int out_size, void* d_ws, size_t ws_size,
                              hipStream_t stream) {
    const float* x     = (const float*)d_in[0];
    const int*   src   = (const int*)  d_in[1];
    const int*   dst   = (const int*)  d_in[2];
    const int*   rel   = (const int*)  d_in[3];
    const float* W_r   = (const float*)d_in[4];
    const float* W_lin = (const float*)d_in[5];
    const float* b_lin = (const float*)d_in[6];
    float* out = (float*)d_out;

    char* ws = (char*)d_ws;
    float* w   = (float*)ws;                      // 1024 floats (4 KB, pad to 4096 B)
    float* agg = (float*)(ws + 4096);             // N_NODES*64 floats
    float* cnt = agg + (size_t)N_NODES * D;       // N_NODES floats

    // zero agg_sum + cnt (contiguous)
    hipMemsetAsync(agg, 0, (size_t)(N_NODES * D + N_NODES) * sizeof(float), stream);

    wprep_kernel<<<4, 256, 0, stream>>>(W_r, w);

    edge_kernel<<<(N_EDGES * 64) / 256, 256, 0, stream>>>(x, src, dst, rel, w, agg, cnt);

    node_kernel<<<(N_NODES + 3) / 4, 256, 0, stream>>>(x, agg, cnt, W_lin, b_lin, out);
}